// Round 9
// baseline (370.414 us; speedup 1.0000x reference)
//
#include <hip/hip_runtime.h>

// DynamicMaskHead: per-instance 3-layer 1x1-conv MLP over [rel_xy, feats] at
// 112x200, then AdelaiDet aligned_bilinear 2x upsample to [n,1,224,400].
//
// R9: latency/flow-bound redesign. Evidence: R5/R7/R8 tie at 38-40us across
// three weight-residency schemes; VALUBusy ~74% is CU-level => per-SIMD ~27%
// (SIMDs mostly idle). Invariant was 256-thr barrier-lockstep blocks with all
// stores bursting in phase C. New structure:
//  - weights staged in LDS (broadcast ds_read_b128; no regalloc fight)
//  - 1-wave (64-thr) blocks, TY=8 (RL=5): 5600 independent waves, ~24
//    blocks/CU resident, natural phase drift -> continuous store flow
//  - single-pass fp32 MLP (absmax back to 9.766e-4)

#define IN_C   8
#define CHN    8
#define Hh     112
#define Ww     200
#define HWp    (Hh * Ww)
#define OH     224
#define OW     400
#define TY     8           // output rows per block
#define RL     5           // logit rows needed (TY/2 + 1)
#define NPIX   (RL * Ww)   // 1000
#define NPAIRS (NPIX / 2)  // 500
#define NTILES (OH / TY)   // 28
#define NPARAMS 169
#define BLK    64

// LDS weight layout (floats):
//  w0p[o][12]: [0]=wx [1]=wy [2..9]=w0[o][0..7] [10]=b0[o] [11]=pad   -> 0..95
//  w1t[i][8] : w1t[i][oo] = w1[oo][i] (transposed for row access)     -> 96..159
//  w2[8] -> 160..167 ; b1[8] -> 168..175 ; b2 -> 176
__device__ __forceinline__ int wmap(int i) {
    if (i < 80)  return (i / 10) * 12 + (i % 10);
    if (i < 144) { const int j = i - 80; return 96 + (j % 8) * 8 + (j / 8); }
    if (i < 152) return 160 + (i - 144);
    if (i < 160) return (i - 152) * 12 + 10;
    if (i < 168) return 168 + (i - 160);
    return 176;
}

__global__ __launch_bounds__(BLK, 6)
void dmh_fused_kernel(const float* __restrict__ feats,      // [4][8][112][200]
                      const float* __restrict__ params,     // [n][169]
                      const float* __restrict__ iloc,       // [n][2]
                      const float* __restrict__ soi_tab,    // [5]
                      const int*   __restrict__ im_inds,    // [n]
                      const int*   __restrict__ fpn_levels, // [n]
                      float* __restrict__ out)              // [n][224][400]
{
    __shared__ float wl[180];          // 720 B (sections 16B-aligned)
    __shared__ float lgt[RL][Ww];      // 4 KB

    const int bid  = blockIdx.x;
    const int inst = bid / NTILES;
    const int ty   = bid - inst * NTILES;
    const int y0   = ty * TY;
    const int r_lo = (y0 > 0 ? (y0 - 1) : 0) >> 1;   // first logit row of tile
    const int tid  = threadIdx.x;

    const float* __restrict__ wp = params + inst * NPARAMS;
    for (int i = tid; i < NPARAMS; i += BLK) wl[wmap(i)] = wp[i];

    const float soi    = soi_tab[fpn_levels[inst]];
    const float inv_s  = 1.0f / soi;
    const float ix     = iloc[inst * 2 + 0];
    const float iy     = iloc[inst * 2 + 1];
    const float* __restrict__ fb = feats + (size_t)im_inds[inst] * (IN_C * HWp);

    __syncthreads();   // 1-wave block: compiles to waitcnt (+no-op barrier)

    // ------------- single pass: logits for rows [r_lo, r_lo+RL) -------------
    for (int p = tid; p < NPAIRS; p += BLK) {
        const int rr = p / (Ww / 2);            // 0..4
        const int c2 = (p - rr * (Ww / 2)) * 2; // 0..198
        const int r  = r_lo + rr;               // <= 111
        const float* fp = fb + r * Ww + c2;

        float fv0[IN_C], fv1[IN_C];
        #pragma unroll
        for (int ch = 0; ch < IN_C; ch++) {
            const float2 t = *reinterpret_cast<const float2*>(fp + ch * HWp);
            fv0[ch] = t.x; fv1[ch] = t.y;
        }
        const float in1  = (iy - (float)(r * 8 + 4)) * inv_s;
        const float in00 = (ix - (float)(c2 * 8 + 4)) * inv_s;
        const float in01 = (ix - (float)(c2 * 8 + 12)) * inv_s;

        float h1a0[CHN], h1a1[CHN];
        #pragma unroll
        for (int o = 0; o < CHN; o++) { h1a0[o] = wl[168 + o]; h1a1[o] = wl[168 + o]; }

        #pragma unroll
        for (int o = 0; o < CHN; o++) {
            const float4 wa = *reinterpret_cast<const float4*>(&wl[o * 12 + 0]);
            const float4 wb = *reinterpret_cast<const float4*>(&wl[o * 12 + 4]);
            const float4 wc = *reinterpret_cast<const float4*>(&wl[o * 12 + 8]);
            // t = b0 + wy*in1 + wx*in0 + sum_i w[i]*f[i]
            const float bo = fmaf(wa.y, in1, wc.z);
            float t0 = fmaf(wa.x, in00, bo);
            float t1 = fmaf(wa.x, in01, bo);
            t0 = fmaf(wa.z, fv0[0], t0);  t1 = fmaf(wa.z, fv1[0], t1);
            t0 = fmaf(wa.w, fv0[1], t0);  t1 = fmaf(wa.w, fv1[1], t1);
            t0 = fmaf(wb.x, fv0[2], t0);  t1 = fmaf(wb.x, fv1[2], t1);
            t0 = fmaf(wb.y, fv0[3], t0);  t1 = fmaf(wb.y, fv1[3], t1);
            t0 = fmaf(wb.z, fv0[4], t0);  t1 = fmaf(wb.z, fv1[4], t1);
            t0 = fmaf(wb.w, fv0[5], t0);  t1 = fmaf(wb.w, fv1[5], t1);
            t0 = fmaf(wc.x, fv0[6], t0);  t1 = fmaf(wc.x, fv1[6], t1);
            t0 = fmaf(wc.y, fv0[7], t0);  t1 = fmaf(wc.y, fv1[7], t1);
            t0 = fmaxf(t0, 0.0f);
            t1 = fmaxf(t1, 0.0f);
            const float4 u0 = *reinterpret_cast<const float4*>(&wl[96 + o * 8 + 0]);
            const float4 u1 = *reinterpret_cast<const float4*>(&wl[96 + o * 8 + 4]);
            h1a0[0] = fmaf(u0.x, t0, h1a0[0]);  h1a1[0] = fmaf(u0.x, t1, h1a1[0]);
            h1a0[1] = fmaf(u0.y, t0, h1a0[1]);  h1a1[1] = fmaf(u0.y, t1, h1a1[1]);
            h1a0[2] = fmaf(u0.z, t0, h1a0[2]);  h1a1[2] = fmaf(u0.z, t1, h1a1[2]);
            h1a0[3] = fmaf(u0.w, t0, h1a0[3]);  h1a1[3] = fmaf(u0.w, t1, h1a1[3]);
            h1a0[4] = fmaf(u1.x, t0, h1a0[4]);  h1a1[4] = fmaf(u1.x, t1, h1a1[4]);
            h1a0[5] = fmaf(u1.y, t0, h1a0[5]);  h1a1[5] = fmaf(u1.y, t1, h1a1[5]);
            h1a0[6] = fmaf(u1.z, t0, h1a0[6]);  h1a1[6] = fmaf(u1.z, t1, h1a1[6]);
            h1a0[7] = fmaf(u1.w, t0, h1a0[7]);  h1a1[7] = fmaf(u1.w, t1, h1a1[7]);
        }
        float r0 = wl[176], r1 = wl[176];
        #pragma unroll
        for (int i = 0; i < CHN; i++) {
            const float w2 = wl[160 + i];
            r0 = fmaf(w2, fmaxf(h1a0[i], 0.0f), r0);
            r1 = fmaf(w2, fmaxf(h1a1[i], 0.0f), r1);
        }
        *reinterpret_cast<float2*>(&lgt[rr][c2]) = make_float2(r0, r1);
    }
    __syncthreads();

    // ============ phase C: aligned 2x bilinear, write 8x400 tile ============
    // out[y][x] = interp[max(y-1,0)][max(x-1,0)], axis weights {1} even / {.5,.5} odd
    float* __restrict__ ob = out + (size_t)inst * (OH * OW);
    const int NQ = (TY * OW) / 4;   // 800 groups of 4 output px
    for (int q = tid; q < NQ; q += BLK) {
        const int dy = q / (OW / 4);            // 0..7
        const int gx = q - dy * (OW / 4);       // 0..99
        const int x  = gx * 4;
        const int y  = y0 + dy;
        const int i  = (y > 0 ? y - 1 : 0);
        const int rr0 = (i >> 1) - r_lo;
        const int r1g = (i >> 1) + (i & 1);
        const int rr1 = (r1g > Hh - 1 ? Hh - 1 : r1g) - r_lo;
        const float wy1 = (i & 1) ? 0.5f : 0.0f;
        const float wy0 = 1.0f - wy1;

        const int cx  = x >> 1;                 // 0..198 (x even)
        const int cm1 = (cx > 0 ? cx - 1 : 0);
        const float a_m = lgt[rr0][cm1], a_0 = lgt[rr0][cx], a_p = lgt[rr0][cx + 1];
        const float b_m = lgt[rr1][cm1], b_0 = lgt[rr1][cx], b_p = lgt[rr1][cx + 1];
        const float Rm = wy0 * a_m + wy1 * b_m;
        const float R0 = wy0 * a_0 + wy1 * b_0;
        const float Rp = wy0 * a_p + wy1 * b_p;

        float4 o4;
        o4.x = 0.5f * (Rm + R0);   // x+0: odd j (clamped at x=0 where Rm==R0)
        o4.y = R0;                 // x+1: exact col cx
        o4.z = 0.5f * (R0 + Rp);   // x+2: odd j
        o4.w = Rp;                 // x+3: exact col cx+1
        *reinterpret_cast<float4*>(&ob[y * OW + x]) = o4;
    }
}

extern "C" void kernel_launch(void* const* d_in, const int* in_sizes, int n_in,
                              void* d_out, int out_size, void* d_ws, size_t ws_size,
                              hipStream_t stream) {
    const float* mask_feats = (const float*)d_in[0];
    const float* params     = (const float*)d_in[1];
    const float* iloc       = (const float*)d_in[2];
    const float* soi        = (const float*)d_in[3];
    const int*   im_inds    = (const int*)d_in[4];
    const int*   fpn        = (const int*)d_in[5];
    // d_in[6] = mask_feat_stride (=8), baked into the kernel constants.
    float* out = (float*)d_out;

    const int n_inst = in_sizes[4];           // 200
    dim3 grid(n_inst * NTILES);               // 5600 blocks
    dim3 block(BLK);
    hipLaunchKernelGGL(dmh_fused_kernel, grid, block, 0, stream,
                       mask_feats, params, iloc, soi, im_inds, fpn, out);
}

// Round 10
// 211.684 us; speedup vs baseline: 1.7498x; 1.7498x over previous
//
#include <hip/hip_runtime.h>

// DynamicMaskHead: per-instance 3-layer 1x1-conv MLP over [rel_xy, feats] at
// 112x200, then AdelaiDet aligned_bilinear 2x upsample to [n,1,224,400].
//
// R10: stall-targeted. Evidence: R8 dynamic==static instrs at 26% per-SIMD
// issue (stall-bound); R9 died of launch_bounds-forced spill (FETCH 1.1GB).
//  - capacity 6 blocks/CU: launch_bounds(256,6) (VGPR cap 85); live set kept
//    small: w0+b0 -> 88 SGPR pins (R7-proven), w1t/w2/b1/b2 -> LDS broadcast
//    (R9-verified wmap layout), 2 px/iter.
//  - software-pipelined feat prefetch: next iteration's 8 float2 loads issued
//    before current iteration's 152 FMAs -> load latency hidden in-wave.
//  - single-pass fp32 MLP (absmax 9.766e-4), TY=16, phase C unchanged.

#define IN_C   8
#define CHN    8
#define Hh     112
#define Ww     200
#define Wh     (Ww / 2)    // 100
#define HWp    (Hh * Ww)
#define OH     224
#define OW     400
#define TY     16          // output rows per block
#define RL     9           // logit rows needed (TY/2 + 1)
#define NPAIRS (RL * Wh)   // 900
#define NTILES (OH / TY)   // 14
#define NPARAMS 169
#define BLK    256

// LDS weight layout (floats) -- verified in R9 (absmax 9.766e-4):
//  w0p[o][12]: [0]=wx [1]=wy [2..9]=w0[o][0..7] [10]=b0[o] [11]=pad -> 0..95 (unused here)
//  w1t[i][8] : w1t[i][oo] = w1[oo][i]                              -> 96..159
//  w2[8] -> 160..167 ; b1[8] -> 168..175 ; b2 -> 176
__device__ __forceinline__ int wmap(int i) {
    if (i < 80)  return (i / 10) * 12 + (i % 10);
    if (i < 144) { const int j = i - 80; return 96 + (j % 8) * 8 + (j / 8); }
    if (i < 152) return 160 + (i - 144);
    if (i < 160) return (i - 152) * 12 + 10;
    if (i < 168) return 168 + (i - 160);
    return 176;
}

__global__ __launch_bounds__(BLK, 6)
void dmh_fused_kernel(const float* __restrict__ feats,      // [4][8][112][200]
                      const float* __restrict__ params,     // [n][169]
                      const float* __restrict__ iloc,       // [n][2]
                      const float* __restrict__ soi_tab,    // [5]
                      const int*   __restrict__ im_inds,    // [n]
                      const int*   __restrict__ fpn_levels, // [n]
                      float* __restrict__ out)              // [n][224][400]
{
    __shared__ float wl[184];          // 736 B
    __shared__ float lgt[RL][Ww];      // 7.2 KB

    const int bid  = blockIdx.x;
    const int inst = bid / NTILES;
    const int ty   = bid - inst * NTILES;
    const int y0   = ty * TY;
    const int r_lo = (y0 > 0 ? (y0 - 1) : 0) >> 1;   // first logit row of tile
    const int tid  = threadIdx.x;

    const float* __restrict__ wp = params + inst * NPARAMS;
    for (int i = tid; i < NPARAMS; i += BLK) wl[wmap(i)] = wp[i];

    // ---- w0 (80) + b0 (8) -> SGPR pins (block-uniform; FMA reads 1 SGPR) ----
    float w0s[80], b0s[CHN];
    #pragma unroll
    for (int i = 0; i < 80; i++) w0s[i] = wp[i];
    #pragma unroll
    for (int i = 0; i < CHN; i++) b0s[i] = wp[152 + i];
    #pragma unroll
    for (int i = 0; i < 80; i++) asm volatile("" : "+s"(w0s[i]));
    #pragma unroll
    for (int i = 0; i < CHN; i++) asm volatile("" : "+s"(b0s[i]));

    const float soi    = soi_tab[fpn_levels[inst]];
    const float inv_s  = 1.0f / soi;
    const float ix     = iloc[inst * 2 + 0];
    const float iy     = iloc[inst * 2 + 1];
    const float* __restrict__ fb = feats + (size_t)im_inds[inst] * (IN_C * HWp);

    __syncthreads();   // wl ready

    // ---------- single pass, software-pipelined: rows [r_lo, r_lo+RL) ----------
    float fv0[IN_C], fv1[IN_C];
    {   // prologue: load pair `tid` (always < NPAIRS)
        const int rr = tid / Wh;
        const int c2 = (tid - rr * Wh) * 2;
        const float* fp = fb + (r_lo + rr) * Ww + c2;
        #pragma unroll
        for (int ch = 0; ch < IN_C; ch++) {
            const float2 t = *reinterpret_cast<const float2*>(fp + ch * HWp);
            fv0[ch] = t.x; fv1[ch] = t.y;
        }
    }
    #pragma unroll 1
    for (int p = tid; p < NPAIRS; ) {
        const int pn = p + BLK;
        float nf0[IN_C], nf1[IN_C];
        if (pn < NPAIRS) {   // prefetch next pair before computing current
            const int rrn = pn / Wh;
            const int c2n = (pn - rrn * Wh) * 2;
            const float* fpn_ = fb + (r_lo + rrn) * Ww + c2n;
            #pragma unroll
            for (int ch = 0; ch < IN_C; ch++) {
                const float2 t = *reinterpret_cast<const float2*>(fpn_ + ch * HWp);
                nf0[ch] = t.x; nf1[ch] = t.y;
            }
        }

        const int rr = p / Wh;
        const int c2 = (p - rr * Wh) * 2;
        const int r  = r_lo + rr;
        const float in1  = (iy - (float)(r * 8 + 4)) * inv_s;
        const float in00 = (ix - (float)(c2 * 8 + 4)) * inv_s;
        const float in01 = (ix - (float)(c2 * 8 + 12)) * inv_s;

        float h1a0[CHN], h1a1[CHN];
        {
            const float4 ba = *reinterpret_cast<const float4*>(&wl[168]);
            const float4 bb = *reinterpret_cast<const float4*>(&wl[172]);
            h1a0[0] = ba.x; h1a0[1] = ba.y; h1a0[2] = ba.z; h1a0[3] = ba.w;
            h1a0[4] = bb.x; h1a0[5] = bb.y; h1a0[6] = bb.z; h1a0[7] = bb.w;
            #pragma unroll
            for (int o = 0; o < CHN; o++) h1a1[o] = h1a0[o];
        }

        #pragma unroll
        for (int o = 0; o < CHN; o++) {
            const float bo = fmaf(w0s[o * 10 + 1], in1, b0s[o]);
            float t0 = fmaf(w0s[o * 10 + 0], in00, bo);
            float t1 = fmaf(w0s[o * 10 + 0], in01, bo);
            #pragma unroll
            for (int i = 0; i < IN_C; i++) {
                t0 = fmaf(w0s[o * 10 + 2 + i], fv0[i], t0);
                t1 = fmaf(w0s[o * 10 + 2 + i], fv1[i], t1);
            }
            t0 = fmaxf(t0, 0.0f);
            t1 = fmaxf(t1, 0.0f);
            const float4 u0 = *reinterpret_cast<const float4*>(&wl[96 + o * 8 + 0]);
            const float4 u1 = *reinterpret_cast<const float4*>(&wl[96 + o * 8 + 4]);
            h1a0[0] = fmaf(u0.x, t0, h1a0[0]);  h1a1[0] = fmaf(u0.x, t1, h1a1[0]);
            h1a0[1] = fmaf(u0.y, t0, h1a0[1]);  h1a1[1] = fmaf(u0.y, t1, h1a1[1]);
            h1a0[2] = fmaf(u0.z, t0, h1a0[2]);  h1a1[2] = fmaf(u0.z, t1, h1a1[2]);
            h1a0[3] = fmaf(u0.w, t0, h1a0[3]);  h1a1[3] = fmaf(u0.w, t1, h1a1[3]);
            h1a0[4] = fmaf(u1.x, t0, h1a0[4]);  h1a1[4] = fmaf(u1.x, t1, h1a1[4]);
            h1a0[5] = fmaf(u1.y, t0, h1a0[5]);  h1a1[5] = fmaf(u1.y, t1, h1a1[5]);
            h1a0[6] = fmaf(u1.z, t0, h1a0[6]);  h1a1[6] = fmaf(u1.z, t1, h1a1[6]);
            h1a0[7] = fmaf(u1.w, t0, h1a0[7]);  h1a1[7] = fmaf(u1.w, t1, h1a1[7]);
        }
        float r0 = wl[176], r1 = wl[176];
        {
            const float4 wa = *reinterpret_cast<const float4*>(&wl[160]);
            const float4 wb = *reinterpret_cast<const float4*>(&wl[164]);
            r0 = fmaf(wa.x, fmaxf(h1a0[0], 0.0f), r0);  r1 = fmaf(wa.x, fmaxf(h1a1[0], 0.0f), r1);
            r0 = fmaf(wa.y, fmaxf(h1a0[1], 0.0f), r0);  r1 = fmaf(wa.y, fmaxf(h1a1[1], 0.0f), r1);
            r0 = fmaf(wa.z, fmaxf(h1a0[2], 0.0f), r0);  r1 = fmaf(wa.z, fmaxf(h1a1[2], 0.0f), r1);
            r0 = fmaf(wa.w, fmaxf(h1a0[3], 0.0f), r0);  r1 = fmaf(wa.w, fmaxf(h1a1[3], 0.0f), r1);
            r0 = fmaf(wb.x, fmaxf(h1a0[4], 0.0f), r0);  r1 = fmaf(wb.x, fmaxf(h1a1[4], 0.0f), r1);
            r0 = fmaf(wb.y, fmaxf(h1a0[5], 0.0f), r0);  r1 = fmaf(wb.y, fmaxf(h1a1[5], 0.0f), r1);
            r0 = fmaf(wb.z, fmaxf(h1a0[6], 0.0f), r0);  r1 = fmaf(wb.z, fmaxf(h1a1[6], 0.0f), r1);
            r0 = fmaf(wb.w, fmaxf(h1a0[7], 0.0f), r0);  r1 = fmaf(wb.w, fmaxf(h1a1[7], 0.0f), r1);
        }
        *reinterpret_cast<float2*>(&lgt[rr][c2]) = make_float2(r0, r1);

        #pragma unroll
        for (int ch = 0; ch < IN_C; ch++) { fv0[ch] = nf0[ch]; fv1[ch] = nf1[ch]; }
        p = pn;
    }
    __syncthreads();

    // ============ phase C: aligned 2x bilinear, write 16x400 tile ============
    // out[y][x] = interp[max(y-1,0)][max(x-1,0)], axis weights {1} even / {.5,.5} odd
    float* __restrict__ ob = out + (size_t)inst * (OH * OW);
    const int NQ = (TY * OW) / 4;   // 1600 groups of 4 output px
    for (int q = tid; q < NQ; q += BLK) {
        const int dy = q / (OW / 4);            // 0..15
        const int gx = q - dy * (OW / 4);       // 0..99
        const int x  = gx * 4;
        const int y  = y0 + dy;
        const int i  = (y > 0 ? y - 1 : 0);
        const int rr0 = (i >> 1) - r_lo;
        const int r1g = (i >> 1) + (i & 1);
        const int rr1 = (r1g > Hh - 1 ? Hh - 1 : r1g) - r_lo;
        const float wy1 = (i & 1) ? 0.5f : 0.0f;
        const float wy0 = 1.0f - wy1;

        const int cx  = x >> 1;                 // 0..198 (x even)
        const int cm1 = (cx > 0 ? cx - 1 : 0);
        const float a_m = lgt[rr0][cm1], a_0 = lgt[rr0][cx], a_p = lgt[rr0][cx + 1];
        const float b_m = lgt[rr1][cm1], b_0 = lgt[rr1][cx], b_p = lgt[rr1][cx + 1];
        const float Rm = wy0 * a_m + wy1 * b_m;
        const float R0 = wy0 * a_0 + wy1 * b_0;
        const float Rp = wy0 * a_p + wy1 * b_p;

        float4 o4;
        o4.x = 0.5f * (Rm + R0);   // x+0: odd j (clamped at x=0 where Rm==R0)
        o4.y = R0;                 // x+1: exact col cx
        o4.z = 0.5f * (R0 + Rp);   // x+2: odd j
        o4.w = Rp;                 // x+3: exact col cx+1
        *reinterpret_cast<float4*>(&ob[y * OW + x]) = o4;
    }
}

extern "C" void kernel_launch(void* const* d_in, const int* in_sizes, int n_in,
                              void* d_out, int out_size, void* d_ws, size_t ws_size,
                              hipStream_t stream) {
    const float* mask_feats = (const float*)d_in[0];
    const float* params     = (const float*)d_in[1];
    const float* iloc       = (const float*)d_in[2];
    const float* soi        = (const float*)d_in[3];
    const int*   im_inds    = (const int*)d_in[4];
    const int*   fpn        = (const int*)d_in[5];
    // d_in[6] = mask_feat_stride (=8), baked into the kernel constants.
    float* out = (float*)d_out;

    const int n_inst = in_sizes[4];           // 200
    dim3 grid(n_inst * NTILES);               // 2800 blocks
    dim3 block(BLK);
    hipLaunchKernelGGL(dmh_fused_kernel, grid, block, 0, stream,
                       mask_feats, params, iloc, soi, im_inds, fpn, out);
}

// Round 11
// 42.197 us; speedup vs baseline: 8.7781x; 5.0165x over previous
//
#include <hip/hip_runtime.h>

// DynamicMaskHead: per-instance 3-layer 1x1-conv MLP over [rel_xy, feats] at
// 112x200, then AdelaiDet aligned_bilinear 2x upsample to [n,1,224,400].
//
// R11: wave-desynchronized structure. Evidence: instr-count changes (R5 vs
// R7), occupancy changes (R8 vs R6) and register-file moves all tie at
// 38-40us; the invariant is block-wide barrier-lockstepped phases => stores
// burst in phase-C windows while phase-A windows leave HBM idle. Here each
// wave owns a private TY=8 tile (RL=5 logit rows, 4KB LDS strip): phase A ->
// s_waitcnt lgkmcnt(0) (wave-local) -> phase C, NO cross-wave barrier after
// weight staging. 1400 blocks all co-resident (single generation, no tail).
// Inner math = R9-verified LDS-weights loop (absmax 9.766e-4). No reg pins,
// no min-waves launch_bounds (R9/R10 spill lessons).

#define IN_C   8
#define CHN    8
#define Hh     112
#define Ww     200
#define Wh     (Ww / 2)    // 100
#define HWp    (Hh * Ww)
#define OH     224
#define OW     400
#define TY     8           // output rows per WAVE
#define RL     5           // logit rows per wave (TY/2 + 1)
#define NPAIRS (RL * Wh)   // 500
#define NTILES (OH / TY)   // 28
#define QUADS  (NTILES/4)  // 7 (4 waves per block)
#define NPARAMS 169
#define BLK    256

// LDS weight layout (floats) -- verified in R9 (absmax 9.766e-4):
//  w0p[o][12]: [0]=wx [1]=wy [2..9]=w0[o][0..7] [10]=b0[o] [11]=pad -> 0..95
//  w1t[i][8] : w1t[i][oo] = w1[oo][i]                              -> 96..159
//  w2[8] -> 160..167 ; b1[8] -> 168..175 ; b2 -> 176
__device__ __forceinline__ int wmap(int i) {
    if (i < 80)  return (i / 10) * 12 + (i % 10);
    if (i < 144) { const int j = i - 80; return 96 + (j % 8) * 8 + (j / 8); }
    if (i < 152) return 160 + (i - 144);
    if (i < 160) return (i - 152) * 12 + 10;
    if (i < 168) return 168 + (i - 160);
    return 176;
}

__global__ __launch_bounds__(BLK)
void dmh_fused_kernel(const float* __restrict__ feats,      // [4][8][112][200]
                      const float* __restrict__ params,     // [n][169]
                      const float* __restrict__ iloc,       // [n][2]
                      const float* __restrict__ soi_tab,    // [5]
                      const int*   __restrict__ im_inds,    // [n]
                      const int*   __restrict__ fpn_levels, // [n]
                      float* __restrict__ out)              // [n][224][400]
{
    __shared__ float wl[184];             // 736 B, shared by all 4 waves
    __shared__ float lgt[4][RL][Ww];      // 16 KB, one strip per wave

    const int bid  = blockIdx.x;
    const int inst = bid / QUADS;
    const int quad = bid - inst * QUADS;
    const int tid  = threadIdx.x;
    const int wid  = tid >> 6;
    const int lane = tid & 63;

    const int ty   = quad * 4 + wid;      // this wave's tile (0..27)
    const int y0   = ty * TY;
    const int r_lo = (y0 > 0 ? (y0 - 1) : 0) >> 1;

    const float* __restrict__ wp = params + inst * NPARAMS;
    for (int i = tid; i < NPARAMS; i += BLK) wl[wmap(i)] = wp[i];

    const float soi    = soi_tab[fpn_levels[inst]];
    const float inv_s  = 1.0f / soi;
    const float ix     = iloc[inst * 2 + 0];
    const float iy     = iloc[inst * 2 + 1];
    const float* __restrict__ fb = feats + (size_t)im_inds[inst] * (IN_C * HWp);

    __syncthreads();   // the only block barrier: wl ready

    // -------- phase A (per-wave): logits for rows [r_lo, r_lo+RL) --------
    float (* __restrict__ lg)[Ww] = lgt[wid];
    for (int p = lane; p < NPAIRS; p += 64) {
        const int rr = p / Wh;              // 0..4
        const int c2 = (p - rr * Wh) * 2;   // 0..198
        const int r  = r_lo + rr;           // <= 111
        const float* fp = fb + r * Ww + c2;

        float fv0[IN_C], fv1[IN_C];
        #pragma unroll
        for (int ch = 0; ch < IN_C; ch++) {
            const float2 t = *reinterpret_cast<const float2*>(fp + ch * HWp);
            fv0[ch] = t.x; fv1[ch] = t.y;
        }
        const float in1  = (iy - (float)(r * 8 + 4)) * inv_s;
        const float in00 = (ix - (float)(c2 * 8 + 4)) * inv_s;
        const float in01 = (ix - (float)(c2 * 8 + 12)) * inv_s;

        float h1a0[CHN], h1a1[CHN];
        #pragma unroll
        for (int o = 0; o < CHN; o++) { h1a0[o] = wl[168 + o]; h1a1[o] = wl[168 + o]; }

        #pragma unroll
        for (int o = 0; o < CHN; o++) {
            const float4 wa = *reinterpret_cast<const float4*>(&wl[o * 12 + 0]);
            const float4 wb = *reinterpret_cast<const float4*>(&wl[o * 12 + 4]);
            const float4 wc = *reinterpret_cast<const float4*>(&wl[o * 12 + 8]);
            const float bo = fmaf(wa.y, in1, wc.z);      // b0 + wy*in1
            float t0 = fmaf(wa.x, in00, bo);
            float t1 = fmaf(wa.x, in01, bo);
            t0 = fmaf(wa.z, fv0[0], t0);  t1 = fmaf(wa.z, fv1[0], t1);
            t0 = fmaf(wa.w, fv0[1], t0);  t1 = fmaf(wa.w, fv1[1], t1);
            t0 = fmaf(wb.x, fv0[2], t0);  t1 = fmaf(wb.x, fv1[2], t1);
            t0 = fmaf(wb.y, fv0[3], t0);  t1 = fmaf(wb.y, fv1[3], t1);
            t0 = fmaf(wb.z, fv0[4], t0);  t1 = fmaf(wb.z, fv1[4], t1);
            t0 = fmaf(wb.w, fv0[5], t0);  t1 = fmaf(wb.w, fv1[5], t1);
            t0 = fmaf(wc.x, fv0[6], t0);  t1 = fmaf(wc.x, fv1[6], t1);
            t0 = fmaf(wc.y, fv0[7], t0);  t1 = fmaf(wc.y, fv1[7], t1);
            t0 = fmaxf(t0, 0.0f);
            t1 = fmaxf(t1, 0.0f);
            const float4 u0 = *reinterpret_cast<const float4*>(&wl[96 + o * 8 + 0]);
            const float4 u1 = *reinterpret_cast<const float4*>(&wl[96 + o * 8 + 4]);
            h1a0[0] = fmaf(u0.x, t0, h1a0[0]);  h1a1[0] = fmaf(u0.x, t1, h1a1[0]);
            h1a0[1] = fmaf(u0.y, t0, h1a0[1]);  h1a1[1] = fmaf(u0.y, t1, h1a1[1]);
            h1a0[2] = fmaf(u0.z, t0, h1a0[2]);  h1a1[2] = fmaf(u0.z, t1, h1a1[2]);
            h1a0[3] = fmaf(u0.w, t0, h1a0[3]);  h1a1[3] = fmaf(u0.w, t1, h1a1[3]);
            h1a0[4] = fmaf(u1.x, t0, h1a0[4]);  h1a1[4] = fmaf(u1.x, t1, h1a1[4]);
            h1a0[5] = fmaf(u1.y, t0, h1a0[5]);  h1a1[5] = fmaf(u1.y, t1, h1a1[5]);
            h1a0[6] = fmaf(u1.z, t0, h1a0[6]);  h1a1[6] = fmaf(u1.z, t1, h1a1[6]);
            h1a0[7] = fmaf(u1.w, t0, h1a0[7]);  h1a1[7] = fmaf(u1.w, t1, h1a1[7]);
        }
        float r0 = wl[176], r1 = wl[176];
        #pragma unroll
        for (int i = 0; i < CHN; i++) {
            const float w2 = wl[160 + i];
            r0 = fmaf(w2, fmaxf(h1a0[i], 0.0f), r0);
            r1 = fmaf(w2, fmaxf(h1a1[i], 0.0f), r1);
        }
        *reinterpret_cast<float2*>(&lg[rr][c2]) = make_float2(r0, r1);
    }

    // wave-local LDS flush: this wave wrote its whole strip itself.
    asm volatile("s_waitcnt lgkmcnt(0)" ::: "memory");

    // -------- phase C (per-wave): aligned 2x bilinear, 8x400 tile --------
    // out[y][x] = interp[max(y-1,0)][max(x-1,0)], weights {1} even / {.5,.5} odd
    float* __restrict__ ob = out + (size_t)inst * (OH * OW);
    const int NQ = (TY * OW) / 4;   // 800 quads
    for (int q = lane; q < NQ; q += 64) {
        const int dy = q / (OW / 4);            // 0..7
        const int gx = q - dy * (OW / 4);       // 0..99
        const int x  = gx * 4;
        const int y  = y0 + dy;
        const int i  = (y > 0 ? y - 1 : 0);
        const int rr0 = (i >> 1) - r_lo;
        const int r1g = (i >> 1) + (i & 1);
        const int rr1 = (r1g > Hh - 1 ? Hh - 1 : r1g) - r_lo;
        const float wy1 = (i & 1) ? 0.5f : 0.0f;
        const float wy0 = 1.0f - wy1;

        const int cx  = x >> 1;                 // 0..198 (x even)
        const int cm1 = (cx > 0 ? cx - 1 : 0);
        const float a_m = lg[rr0][cm1], a_0 = lg[rr0][cx], a_p = lg[rr0][cx + 1];
        const float b_m = lg[rr1][cm1], b_0 = lg[rr1][cx], b_p = lg[rr1][cx + 1];
        const float Rm = wy0 * a_m + wy1 * b_m;
        const float R0 = wy0 * a_0 + wy1 * b_0;
        const float Rp = wy0 * a_p + wy1 * b_p;

        float4 o4;
        o4.x = 0.5f * (Rm + R0);   // x+0: odd j (clamped at x=0 where Rm==R0)
        o4.y = R0;                 // x+1: exact col cx
        o4.z = 0.5f * (R0 + Rp);   // x+2: odd j
        o4.w = Rp;                 // x+3: exact col cx+1
        *reinterpret_cast<float4*>(&ob[y * OW + x]) = o4;
    }
}

extern "C" void kernel_launch(void* const* d_in, const int* in_sizes, int n_in,
                              void* d_out, int out_size, void* d_ws, size_t ws_size,
                              hipStream_t stream) {
    const float* mask_feats = (const float*)d_in[0];
    const float* params     = (const float*)d_in[1];
    const float* iloc       = (const float*)d_in[2];
    const float* soi        = (const float*)d_in[3];
    const int*   im_inds    = (const int*)d_in[4];
    const int*   fpn        = (const int*)d_in[5];
    // d_in[6] = mask_feat_stride (=8), baked into the kernel constants.
    float* out = (float*)d_out;

    const int n_inst = in_sizes[4];           // 200
    dim3 grid(n_inst * QUADS);                // 1400 blocks (4 tiles each)
    dim3 block(BLK);
    hipLaunchKernelGGL(dmh_fused_kernel, grid, block, 0, stream,
                       mask_feats, params, iloc, soi, im_inds, fpn, out);
}